// Round 6
// baseline (148.211 us; speedup 1.0000x reference)
//
#include <hip/hip_runtime.h>
#include <math.h>

// Problem dims
#define NB    2
#define LSEQ  256
#define HDIM  256
#define IDIM  512
#define NROW  512      // NB*LSEQ
#define ESZ   1536     // effective fused ssm/gate output cols
#define NC    8        // scan chunks
#define TCH   32       // chunk length (NC*TCH == LSEQ)

typedef __attribute__((ext_vector_type(8))) short bf16x8;
typedef __attribute__((ext_vector_type(4))) float f32x4;

__device__ inline unsigned short f2b(float f) {
    unsigned u = __float_as_uint(f);
    return (unsigned short)((u + 0x7FFFu + ((u >> 16) & 1u)) >> 16);
}

// ---------------------------------------------------------------------------
// kcvt: convert x, W_in, conv_w (3 transposed planes), fused Wsg, bsg, W_out
// to bf16 staging buffers. Memory-bound, grid-stride.
// ---------------------------------------------------------------------------
__global__ __launch_bounds__(256) void kcvt(const float* __restrict__ x,
                                            const float* __restrict__ W_in,
                                            const float* __restrict__ conv_w,
                                            const float* __restrict__ W_ssm,
                                            const float* __restrict__ W_gate,
                                            const float* __restrict__ b_ssm,
                                            const float* __restrict__ b_gate,
                                            const float* __restrict__ W_out,
                                            unsigned short* __restrict__ xb,
                                            unsigned short* __restrict__ Wb,
                                            unsigned short* __restrict__ cwb,
                                            unsigned short* __restrict__ Wsgb,
                                            float* __restrict__ bsg,
                                            unsigned short* __restrict__ W_outb) {
    const int stride = gridDim.x * 256;
    const int t0 = blockIdx.x * 256 + threadIdx.x;
    for (int i = t0; i < 131072; i += stride) xb[i] = f2b(x[i]);
    for (int i = t0; i < 262144; i += stride) Wb[i] = f2b(W_in[i]);
    // cwb[k][o][i] = conv_w[o][i][k]; thread handles one (o,i), 3 planes
    for (int d = t0; d < 262144; d += stride) {
        const float* s = conv_w + (size_t)d * 3;
        cwb[d]          = f2b(s[0]);
        cwb[262144 + d] = f2b(s[1]);
        cwb[524288 + d] = f2b(s[2]);
    }
    // Wsgb rows: 0..1023 = W_ssm[512..1535]; 1024..1535 = W_gate[512..1023]
    for (int d = t0; d < 786432; d += stride) {
        int j = d >> 9, i = d & 511;
        float v = (j < 1024) ? W_ssm[(size_t)(512 + j) * 512 + i]
                             : W_gate[(size_t)(j - 512) * 512 + i];
        Wsgb[d] = f2b(v);
    }
    for (int j = t0; j < 1536; j += stride)
        bsg[j] = (j < 1024) ? b_ssm[512 + j] : b_gate[j - 512];
    for (int i = t0; i < 131072; i += stride) W_outb[i] = f2b(W_out[i]);
}

// ---------------------------------------------------------------------------
// k1: xp = x @ W_in^T (512x1024, K=256). Wave per 16x16 tile, no LDS.
// ---------------------------------------------------------------------------
__global__ __launch_bounds__(256) void k1_mfma(const unsigned short* __restrict__ xb,
                                               const unsigned short* __restrict__ Wb,
                                               float* __restrict__ xq_g,
                                               unsigned short* __restrict__ xkb) {
    const int t = threadIdx.x;
    const int w = blockIdx.x * 4 + (t >> 6);   // 0..2047
    const int lane = t & 63;
    const int mt = w >> 6, nt = w & 63;
    const int r0 = mt * 16, n0 = nt * 16;
    const int fr = lane & 15, fk = (lane >> 4) * 8;
    const unsigned short* ap = xb + (size_t)(r0 + fr) * HDIM + fk;
    const unsigned short* bp = Wb + (size_t)(n0 + fr) * HDIM + fk;
    f32x4 acc = {0.f, 0.f, 0.f, 0.f};
    #pragma unroll
    for (int k0 = 0; k0 < HDIM; k0 += 32) {
        bf16x8 av = *(const bf16x8*)(ap + k0);
        bf16x8 bv = *(const bf16x8*)(bp + k0);
        acc = __builtin_amdgcn_mfma_f32_16x16x32_bf16(av, bv, acc, 0, 0, 0);
    }
    const int orow = (lane >> 4) * 4;
    const int oc = n0 + fr;
    if (oc < IDIM) {
        #pragma unroll
        for (int j = 0; j < 4; ++j) {
            float v = acc[j];
            xq_g[(size_t)(r0 + orow + j) * IDIM + oc] =
                0.5f * v * (1.0f + erff(v * 0.70710678118654752f));
        }
    } else {
        #pragma unroll
        for (int j = 0; j < 4; ++j)
            xkb[(size_t)(r0 + orow + j) * IDIM + (oc - IDIM)] = f2b(acc[j]);
    }
}

// ---------------------------------------------------------------------------
// kxc: xc[r,o] = gelu_q[r,o] + conv_b[o] + sum_k xk[r+k-1,:]·cwb[k][o,:]
// ---------------------------------------------------------------------------
__global__ __launch_bounds__(256) void kxc_mfma(const unsigned short* __restrict__ xkb,
                                                const unsigned short* __restrict__ cwb,
                                                const float* __restrict__ xq_g,
                                                const float* __restrict__ conv_b,
                                                float* __restrict__ xc,
                                                unsigned short* __restrict__ xcb) {
    const int t = threadIdx.x;
    const int w = blockIdx.x * 4 + (t >> 6);   // 0..1023
    const int lane = t & 63;
    const int mt = w >> 5, nt = w & 31;
    const int r0 = mt * 16, o0 = nt * 16;
    const int fr = lane & 15, fk = (lane >> 4) * 8;
    const int g = r0 + fr;
    const int lo = r0 & ~255, hi = lo + 256;
    const bool okm = (g - 1 >= lo), okp = (g + 1 < hi);
    const unsigned short* am = xkb + (size_t)(g - 1) * IDIM + fk;
    const unsigned short* a0 = xkb + (size_t)g * IDIM + fk;
    const unsigned short* ap = xkb + (size_t)(g + 1) * IDIM + fk;
    const unsigned short* b0 = cwb + (size_t)(o0 + fr) * IDIM + fk;
    const unsigned short* b1 = b0 + 262144;
    const unsigned short* b2 = b0 + 524288;
    const bf16x8 zz = {0, 0, 0, 0, 0, 0, 0, 0};
    f32x4 acc = {0.f, 0.f, 0.f, 0.f};
    #pragma unroll
    for (int k0 = 0; k0 < IDIM; k0 += 32) {
        bf16x8 avm = okm ? *(const bf16x8*)(am + k0) : zz;
        bf16x8 av0 = *(const bf16x8*)(a0 + k0);
        bf16x8 avp = okp ? *(const bf16x8*)(ap + k0) : zz;
        bf16x8 bv0 = *(const bf16x8*)(b0 + k0);
        bf16x8 bv1 = *(const bf16x8*)(b1 + k0);
        bf16x8 bv2 = *(const bf16x8*)(b2 + k0);
        acc = __builtin_amdgcn_mfma_f32_16x16x32_bf16(avm, bv0, acc, 0, 0, 0);
        acc = __builtin_amdgcn_mfma_f32_16x16x32_bf16(av0, bv1, acc, 0, 0, 0);
        acc = __builtin_amdgcn_mfma_f32_16x16x32_bf16(avp, bv2, acc, 0, 0, 0);
    }
    const int orow = (lane >> 4) * 4;
    const int oc = o0 + fr;
    const float cb = conv_b[oc];
    #pragma unroll
    for (int j = 0; j < 4; ++j) {
        int r = r0 + orow + j;
        float v = acc[j] + xq_g[(size_t)r * IDIM + oc] + cb;
        xc[(size_t)r * IDIM + oc] = v;
        xcb[(size_t)r * IDIM + oc] = f2b(v);
    }
}

// ---------------------------------------------------------------------------
// k3: E = xc @ Wsg^T + bsg  (512x1536, K=512). Wave per 16x16 tile.
// ---------------------------------------------------------------------------
__global__ __launch_bounds__(256) void k3_mfma(const unsigned short* __restrict__ xcb,
                                               const unsigned short* __restrict__ Wsgb,
                                               const float* __restrict__ bsg,
                                               float* __restrict__ E) {
    const int t = threadIdx.x;
    const int w = blockIdx.x * 4 + (t >> 6);   // 0..3071
    const int lane = t & 63;
    const int mt = w / 96, nt = w % 96;
    const int r0 = mt * 16, j0 = nt * 16;
    const int fr = lane & 15, fk = (lane >> 4) * 8;
    const unsigned short* ap = xcb + (size_t)(r0 + fr) * IDIM + fk;
    const unsigned short* bp = Wsgb + (size_t)(j0 + fr) * IDIM + fk;
    f32x4 acc = {0.f, 0.f, 0.f, 0.f};
    #pragma unroll
    for (int k0 = 0; k0 < IDIM; k0 += 32) {
        bf16x8 av = *(const bf16x8*)(ap + k0);
        bf16x8 bv = *(const bf16x8*)(bp + k0);
        acc = __builtin_amdgcn_mfma_f32_16x16x32_bf16(av, bv, acc, 0, 0, 0);
    }
    const int orow = (lane >> 4) * 4;
    const int jc = j0 + fr;
    const float bias = bsg[jc];
    #pragma unroll
    for (int j = 0; j < 4; ++j)
        E[(size_t)(r0 + orow + j) * ESZ + jc] = acc[j] + bias;
}

// ---------------------------------------------------------------------------
// K3b: Cw[r,s] = sigmoid(E[r,1024+s]) * E[r,s];  u[r,i] = xc[r,i]*E[r,512+i]^2
// ---------------------------------------------------------------------------
__global__ __launch_bounds__(256) void k3b_elem(const float* __restrict__ E,
                                                const float* __restrict__ xc,
                                                float* __restrict__ Cw,
                                                float* __restrict__ u) {
    int idx4 = (blockIdx.x * 256 + threadIdx.x) * 4;  // < 512*512
    int r = idx4 >> 9, s = idx4 & 511;
    const float* Er = E + (size_t)r * ESZ;
    float4 craw = *(const float4*)&Er[s];
    float4 dw   = *(const float4*)&Er[512 + s];
    float4 graw = *(const float4*)&Er[1024 + s];
    float4 xcv  = *(const float4*)&xc[idx4];
    float4 cw, uv;
    cw.x = craw.x / (1.0f + expf(-graw.x));
    cw.y = craw.y / (1.0f + expf(-graw.y));
    cw.z = craw.z / (1.0f + expf(-graw.z));
    cw.w = craw.w / (1.0f + expf(-graw.w));
    uv.x = xcv.x * dw.x * dw.x;
    uv.y = xcv.y * dw.y * dw.y;
    uv.z = xcv.z * dw.z * dw.z;
    uv.w = xcv.w * dw.w * dw.w;
    *(float4*)&Cw[idx4] = cw;
    *(float4*)&u[idx4]  = uv;
}

// ---------------------------------------------------------------------------
// K4a: chunk-local scan from h=0; write chunk-final carry C_loc[b][c][i][s].
// Wave per (b,c,i); lane owns 8 s-values. NC=8, TCH=32 -> 8192 waves.
// ---------------------------------------------------------------------------
__global__ __launch_bounds__(256) void k4a_pass1(const float* __restrict__ u,
                                                 const float* __restrict__ A,
                                                 float* __restrict__ C_loc) {
    const int wave = (blockIdx.x * 256 + threadIdx.x) >> 6;  // 0..8191
    const int lane = threadIdx.x & 63;
    const int i = wave & 511;
    const int c = (wave >> 9) & (NC - 1);
    const int b = wave >> 12;
    const int s8 = lane * 8;
    float a[8], h[8];
    #pragma unroll
    for (int j = 0; j < 8; ++j) {
        a[j] = A[(size_t)(s8 + j) * IDIM + i];
        h[j] = 0.0f;
    }
    const float* ub = u + ((size_t)b * LSEQ + c * TCH) * IDIM;
    #pragma unroll 4
    for (int l = 0; l < TCH; ++l) {
        float4 u0 = *(const float4*)(ub + l * IDIM + s8);
        float4 u1 = *(const float4*)(ub + l * IDIM + s8 + 4);
        h[0] = h[0] * a[0] + u0.x; h[1] = h[1] * a[1] + u0.y;
        h[2] = h[2] * a[2] + u0.z; h[3] = h[3] * a[3] + u0.w;
        h[4] = h[4] * a[4] + u1.x; h[5] = h[5] * a[5] + u1.y;
        h[6] = h[6] * a[6] + u1.z; h[7] = h[7] * a[7] + u1.w;
    }
    float* cp = C_loc + (((size_t)b * NC + c) * IDIM + i) * IDIM + s8;
    float4 v0, v1;
    v0.x = h[0]; v0.y = h[1]; v0.z = h[2]; v0.w = h[3];
    v1.x = h[4]; v1.y = h[5]; v1.z = h[6]; v1.w = h[7];
    *(float4*)cp = v0;
    *(float4*)(cp + 4) = v1;
}

// ---------------------------------------------------------------------------
// K4b: sequential combine IN-PLACE: C_loc[b][c] is replaced by the state
// ENTERING chunk c. h_{c} = h_{c-1} * A^TCH + carry_{c-1}, h_0 = 0.
// ---------------------------------------------------------------------------
__global__ __launch_bounds__(256) void k4b_combine(const float* __restrict__ A,
                                                   float* __restrict__ C_loc) {
    int idx = blockIdx.x * 256 + threadIdx.x;   // < 2*512*128
    int s4 = (idx & 127) * 4;
    int i  = (idx >> 7) & 511;
    int b  = idx >> 16;
    float da[4], h4[4] = {0.0f, 0.0f, 0.0f, 0.0f};
    #pragma unroll
    for (int j = 0; j < 4; ++j) {
        float aa = A[(size_t)(s4 + j) * IDIM + i];
        aa = aa * aa; aa = aa * aa; aa = aa * aa;
        aa = aa * aa; aa = aa * aa;                 // ^32 == TCH
        da[j] = aa;
    }
    for (int c = 0; c < NC; ++c) {
        size_t base = (((size_t)b * NC + c) * IDIM + i) * IDIM + s4;
        float4 cl = *(const float4*)&C_loc[base];   // carry of chunk c
        float4 hv;
        hv.x = h4[0]; hv.y = h4[1]; hv.z = h4[2]; hv.w = h4[3];
        *(float4*)&C_loc[base] = hv;                // state entering chunk c
        h4[0] = h4[0] * da[0] + cl.x;
        h4[1] = h4[1] * da[1] + cl.y;
        h4[2] = h4[2] * da[2] + cl.z;
        h4[3] = h4[3] * da[3] + cl.w;
    }
}

// ---------------------------------------------------------------------------
// K4c: seeded chunk scan + contraction; 8 l-steps per butterfly batch.
// ---------------------------------------------------------------------------
__global__ __launch_bounds__(256) void k4c_pass2(const float* __restrict__ u,
                                                 const float* __restrict__ Cw,
                                                 const float* __restrict__ A,
                                                 const float* __restrict__ D,
                                                 const float* __restrict__ H,
                                                 unsigned short* __restrict__ ybb) {
    const int wave = (blockIdx.x * 256 + threadIdx.x) >> 6;  // 0..8191
    const int lane = threadIdx.x & 63;
    const int i = wave & 511;
    const int c = (wave >> 9) & (NC - 1);
    const int b = wave >> 12;
    const int s8 = lane * 8;
    float a[8], h[8];
    #pragma unroll
    for (int j = 0; j < 8; ++j) a[j] = A[(size_t)(s8 + j) * IDIM + i];
    const float* hp = H + (((size_t)b * NC + c) * IDIM + i) * IDIM + s8;
    float4 h0v = *(const float4*)hp;
    float4 h1v = *(const float4*)(hp + 4);
    h[0] = h0v.x; h[1] = h0v.y; h[2] = h0v.z; h[3] = h0v.w;
    h[4] = h1v.x; h[5] = h1v.y; h[6] = h1v.z; h[7] = h1v.w;
    const float Di = D[i];
    const float* ub = u + (size_t)b * LSEQ * IDIM;
    const float* cb = Cw + (size_t)b * LSEQ * IDIM;
    unsigned short* yb = ybb + (size_t)b * LSEQ * IDIM;
    for (int l0 = c * TCH; l0 < c * TCH + TCH; l0 += 8) {
        float p[8];
        #pragma unroll
        for (int j = 0; j < 8; ++j) {
            const int l = l0 + j;
            const float4* up = (const float4*)(ub + l * IDIM + s8);
            const float4* cp = (const float4*)(cb + l * IDIM + s8);
            float4 u0 = up[0], u1 = up[1];
            float4 c0 = cp[0], c1 = cp[1];
            h[0] = h[0] * a[0] + u0.x; h[1] = h[1] * a[1] + u0.y;
            h[2] = h[2] * a[2] + u0.z; h[3] = h[3] * a[3] + u0.w;
            h[4] = h[4] * a[4] + u1.x; h[5] = h[5] * a[5] + u1.y;
            h[6] = h[6] * a[6] + u1.z; h[7] = h[7] * a[7] + u1.w;
            float p0 = c0.x * h[0] + c0.y * h[1] + c0.z * h[2] + c0.w * h[3];
            float p1 = c1.x * h[4] + c1.y * h[5] + c1.z * h[6] + c1.w * h[7];
            p[j] = p0 + p1;
        }
        #pragma unroll
        for (int off = 1; off < 64; off <<= 1) {
            #pragma unroll
            for (int j = 0; j < 8; ++j) p[j] += __shfl_xor(p[j], off, 64);
        }
        if (lane == 0) {
            #pragma unroll
            for (int j = 0; j < 8; ++j)
                yb[(l0 + j) * IDIM + i] = f2b(p[j] + ub[(l0 + j) * IDIM + i] * Di);
        }
    }
}

// ---------------------------------------------------------------------------
// k5a: outlin = y @ W_out^T (512x256, K=512). Wave per 16x16 tile.
// ---------------------------------------------------------------------------
__global__ __launch_bounds__(256) void k5a_mfma(const unsigned short* __restrict__ ybb,
                                                const unsigned short* __restrict__ W_outb,
                                                float* __restrict__ outlin) {
    const int t = threadIdx.x;
    const int w = blockIdx.x * 4 + (t >> 6);   // 0..511
    const int lane = t & 63;
    const int mt = w >> 4, nt = w & 15;
    const int r0 = mt * 16, h0 = nt * 16;
    const int fr = lane & 15, fk = (lane >> 4) * 8;
    const unsigned short* ap = ybb + (size_t)(r0 + fr) * IDIM + fk;
    const unsigned short* bp = W_outb + (size_t)(h0 + fr) * IDIM + fk;
    f32x4 acc = {0.f, 0.f, 0.f, 0.f};
    #pragma unroll
    for (int k0 = 0; k0 < IDIM; k0 += 32) {
        bf16x8 av = *(const bf16x8*)(ap + k0);
        bf16x8 bv = *(const bf16x8*)(bp + k0);
        acc = __builtin_amdgcn_mfma_f32_16x16x32_bf16(av, bv, acc, 0, 0, 0);
    }
    const int orow = (lane >> 4) * 4;
    const int hc = h0 + fr;
    #pragma unroll
    for (int j = 0; j < 4; ++j)
        outlin[(size_t)(r0 + orow + j) * HDIM + hc] = acc[j];
}

// ---------------------------------------------------------------------------
// K5b: LayerNorm over H=256 + z scale + residual. One block per row.
// ---------------------------------------------------------------------------
__global__ __launch_bounds__(256) void k5b_ln(const float* __restrict__ outlin,
                                              const float* __restrict__ x,
                                              const float* __restrict__ z,
                                              const float* __restrict__ ln_g,
                                              const float* __restrict__ ln_b,
                                              float* __restrict__ out) {
    const int r = blockIdx.x;
    const int t = threadIdx.x;
    float v = outlin[(size_t)r * HDIM + t];
    float s1 = v, s2 = v * v;
    #pragma unroll
    for (int off = 1; off < 64; off <<= 1) {
        s1 += __shfl_xor(s1, off, 64);
        s2 += __shfl_xor(s2, off, 64);
    }
    __shared__ float r1[4], r2[4];
    const int w = t >> 6, lane = t & 63;
    if (lane == 0) { r1[w] = s1; r2[w] = s2; }
    __syncthreads();
    float t1 = r1[0] + r1[1] + r1[2] + r1[3];
    float t2 = r2[0] + r2[1] + r2[2] + r2[3];
    float mu = t1 * (1.0f / 256.0f);
    float var = t2 * (1.0f / 256.0f) - mu * mu;
    float inv = rsqrtf(var + 1e-5f);
    float o = (v - mu) * inv * ln_g[t] + ln_b[t];
    out[(size_t)r * HDIM + t] = o * z[0] + x[(size_t)r * HDIM + t];
}

// ---------------------------------------------------------------------------
extern "C" void kernel_launch(void* const* d_in, const int* in_sizes, int n_in,
                              void* d_out, int out_size, void* d_ws, size_t ws_size,
                              hipStream_t stream) {
    const float* x      = (const float*)d_in[0];
    const float* W_in   = (const float*)d_in[1];
    const float* conv_w = (const float*)d_in[2];
    const float* conv_b = (const float*)d_in[3];
    const float* W_ssm  = (const float*)d_in[4];
    const float* b_ssm  = (const float*)d_in[5];
    const float* W_gate = (const float*)d_in[6];
    const float* b_gate = (const float*)d_in[7];
    const float* A      = (const float*)d_in[8];
    const float* D      = (const float*)d_in[9];
    const float* W_out  = (const float*)d_in[10];
    const float* z      = (const float*)d_in[11];
    const float* ln_g   = (const float*)d_in[12];
    const float* ln_b   = (const float*)d_in[13];
    float* out = (float*)d_out;

    float* ws = (float*)d_ws;
    float*          xq_g   = ws;                               // 262144 f32
    float*          xc     = ws + 262144;                      // 262144 f32
    float*          E      = ws + 524288;                      // 786432 f32
    float*          Cw     = ws + 1310720;                     // 262144 f32
    float*          u      = ws + 1572864;                     // 262144 f32
    float*          outlin = ws + 1835008;                     // 131072 f32
    float*          bsg    = ws + 1966080;                     // 2048 f32 (1536 used)
    unsigned short* xcb    = (unsigned short*)(ws + 1968128);  // 262144 bf16
    unsigned short* xkb    = (unsigned short*)(ws + 2099200);  // 262144 bf16
    unsigned short* Wsgb   = (unsigned short*)(ws + 2230272);  // 786432 bf16
    unsigned short* W_outb = (unsigned short*)(ws + 2623488);  // 131072 bf16
    unsigned short* ybb    = (unsigned short*)(ws + 2689024);  // 262144 bf16
    // AREA: {xb, Wb, cwb} dead after kxc; reused for C_loc (NC=8, in-place H)
    float*          area   = ws + 2820096;                     // 4194304 f32
    unsigned short* xb     = (unsigned short*)area;            // 131072 bf16
    unsigned short* Wb     = (unsigned short*)(area + 65536);  // 262144 bf16
    unsigned short* cwb    = (unsigned short*)(area + 196608); // 786432 bf16
    float*          C_loc  = area;                             // 2*8*512*512 = 4194304 f32

    kcvt      <<<512, 256, 0, stream>>>(x, W_in, conv_w, W_ssm, W_gate, b_ssm,
                                        b_gate, W_out, xb, Wb, cwb, Wsgb, bsg, W_outb);
    k1_mfma   <<<512, 256, 0, stream>>>(xb, Wb, xq_g, xkb);
    kxc_mfma  <<<256, 256, 0, stream>>>(xkb, cwb, xq_g, conv_b, xc, xcb);
    k3_mfma   <<<768, 256, 0, stream>>>(xcb, Wsgb, bsg, E);
    k3b_elem  <<<256, 256, 0, stream>>>(E, xc, Cw, u);
    k4a_pass1 <<<2048, 256, 0, stream>>>(u, A, C_loc);
    k4b_combine<<<512, 256, 0, stream>>>(A, C_loc);
    k4c_pass2 <<<2048, 256, 0, stream>>>(u, Cw, A, D, C_loc, ybb);
    k5a_mfma  <<<128, 256, 0, stream>>>(ybb, W_outb, outlin);
    k5b_ln    <<<512, 256, 0, stream>>>(outlin, x, z, ln_g, ln_b, out);
}

// Round 7
// 104.153 us; speedup vs baseline: 1.4230x; 1.4230x over previous
//
#include <hip/hip_runtime.h>
#include <math.h>

// Problem dims
#define NB    2
#define LSEQ  256
#define HDIM  256
#define IDIM  512
#define NROW  512      // NB*LSEQ
#define ESZ   1536     // effective fused ssm/gate output cols
#define NC    8        // scan chunks
#define TCH   32       // chunk length (NC*TCH == LSEQ)

typedef __attribute__((ext_vector_type(8))) short bf16x8;
typedef __attribute__((ext_vector_type(4))) float f32x4;

__device__ inline unsigned short f2b(float f) {
    unsigned u = __float_as_uint(f);
    return (unsigned short)((u + 0x7FFFu + ((u >> 16) & 1u)) >> 16);
}

// ---------------------------------------------------------------------------
// kcvt: convert x, W_in, conv_w (3 transposed planes), fused Wsg, bsg, W_out
// to bf16 staging buffers. Memory-bound, grid-stride.
// ---------------------------------------------------------------------------
__global__ __launch_bounds__(256) void kcvt(const float* __restrict__ x,
                                            const float* __restrict__ W_in,
                                            const float* __restrict__ conv_w,
                                            const float* __restrict__ W_ssm,
                                            const float* __restrict__ W_gate,
                                            const float* __restrict__ b_ssm,
                                            const float* __restrict__ b_gate,
                                            const float* __restrict__ W_out,
                                            unsigned short* __restrict__ xb,
                                            unsigned short* __restrict__ Wb,
                                            unsigned short* __restrict__ cwb,
                                            unsigned short* __restrict__ Wsgb,
                                            float* __restrict__ bsg,
                                            unsigned short* __restrict__ W_outb) {
    const int stride = gridDim.x * 256;
    const int t0 = blockIdx.x * 256 + threadIdx.x;
    for (int i = t0; i < 131072; i += stride) xb[i] = f2b(x[i]);
    for (int i = t0; i < 262144; i += stride) Wb[i] = f2b(W_in[i]);
    // cwb[k][o][i] = conv_w[o][i][k]; thread handles one (o,i), 3 planes
    for (int d = t0; d < 262144; d += stride) {
        const float* s = conv_w + (size_t)d * 3;
        cwb[d]          = f2b(s[0]);
        cwb[262144 + d] = f2b(s[1]);
        cwb[524288 + d] = f2b(s[2]);
    }
    // Wsgb rows: 0..1023 = W_ssm[512..1535]; 1024..1535 = W_gate[512..1023]
    for (int d = t0; d < 786432; d += stride) {
        int j = d >> 9, i = d & 511;
        float v = (j < 1024) ? W_ssm[(size_t)(512 + j) * 512 + i]
                             : W_gate[(size_t)(j - 512) * 512 + i];
        Wsgb[d] = f2b(v);
    }
    for (int j = t0; j < 1536; j += stride)
        bsg[j] = (j < 1024) ? b_ssm[512 + j] : b_gate[j - 512];
    for (int i = t0; i < 131072; i += stride) W_outb[i] = f2b(W_out[i]);
}

// ---------------------------------------------------------------------------
// k1: xp = x @ W_in^T (512x1024, K=256). Wave per 16x16 tile, no LDS.
// ---------------------------------------------------------------------------
__global__ __launch_bounds__(256) void k1_mfma(const unsigned short* __restrict__ xb,
                                               const unsigned short* __restrict__ Wb,
                                               float* __restrict__ xq_g,
                                               unsigned short* __restrict__ xkb) {
    const int t = threadIdx.x;
    const int w = blockIdx.x * 4 + (t >> 6);   // 0..2047
    const int lane = t & 63;
    const int mt = w >> 6, nt = w & 63;
    const int r0 = mt * 16, n0 = nt * 16;
    const int fr = lane & 15, fk = (lane >> 4) * 8;
    const unsigned short* ap = xb + (size_t)(r0 + fr) * HDIM + fk;
    const unsigned short* bp = Wb + (size_t)(n0 + fr) * HDIM + fk;
    f32x4 acc = {0.f, 0.f, 0.f, 0.f};
    #pragma unroll
    for (int k0 = 0; k0 < HDIM; k0 += 32) {
        bf16x8 av = *(const bf16x8*)(ap + k0);
        bf16x8 bv = *(const bf16x8*)(bp + k0);
        acc = __builtin_amdgcn_mfma_f32_16x16x32_bf16(av, bv, acc, 0, 0, 0);
    }
    const int orow = (lane >> 4) * 4;
    const int oc = n0 + fr;
    if (oc < IDIM) {
        #pragma unroll
        for (int j = 0; j < 4; ++j) {
            float v = acc[j];
            xq_g[(size_t)(r0 + orow + j) * IDIM + oc] =
                0.5f * v * (1.0f + erff(v * 0.70710678118654752f));
        }
    } else {
        #pragma unroll
        for (int j = 0; j < 4; ++j)
            xkb[(size_t)(r0 + orow + j) * IDIM + (oc - IDIM)] = f2b(acc[j]);
    }
}

// ---------------------------------------------------------------------------
// kxc: xc[r,o] = gelu_q[r,o] + conv_b[o] + sum_k xk[r+k-1,:]·cwb[k][o,:]
// ---------------------------------------------------------------------------
__global__ __launch_bounds__(256) void kxc_mfma(const unsigned short* __restrict__ xkb,
                                                const unsigned short* __restrict__ cwb,
                                                const float* __restrict__ xq_g,
                                                const float* __restrict__ conv_b,
                                                float* __restrict__ xc,
                                                unsigned short* __restrict__ xcb) {
    const int t = threadIdx.x;
    const int w = blockIdx.x * 4 + (t >> 6);   // 0..1023
    const int lane = t & 63;
    const int mt = w >> 5, nt = w & 31;
    const int r0 = mt * 16, o0 = nt * 16;
    const int fr = lane & 15, fk = (lane >> 4) * 8;
    const int g = r0 + fr;
    const int lo = r0 & ~255, hi = lo + 256;
    const bool okm = (g - 1 >= lo), okp = (g + 1 < hi);
    const unsigned short* am = xkb + (size_t)(g - 1) * IDIM + fk;
    const unsigned short* a0 = xkb + (size_t)g * IDIM + fk;
    const unsigned short* ap = xkb + (size_t)(g + 1) * IDIM + fk;
    const unsigned short* b0 = cwb + (size_t)(o0 + fr) * IDIM + fk;
    const unsigned short* b1 = b0 + 262144;
    const unsigned short* b2 = b0 + 524288;
    const bf16x8 zz = {0, 0, 0, 0, 0, 0, 0, 0};
    f32x4 acc = {0.f, 0.f, 0.f, 0.f};
    #pragma unroll
    for (int k0 = 0; k0 < IDIM; k0 += 32) {
        bf16x8 avm = okm ? *(const bf16x8*)(am + k0) : zz;
        bf16x8 av0 = *(const bf16x8*)(a0 + k0);
        bf16x8 avp = okp ? *(const bf16x8*)(ap + k0) : zz;
        bf16x8 bv0 = *(const bf16x8*)(b0 + k0);
        bf16x8 bv1 = *(const bf16x8*)(b1 + k0);
        bf16x8 bv2 = *(const bf16x8*)(b2 + k0);
        acc = __builtin_amdgcn_mfma_f32_16x16x32_bf16(avm, bv0, acc, 0, 0, 0);
        acc = __builtin_amdgcn_mfma_f32_16x16x32_bf16(av0, bv1, acc, 0, 0, 0);
        acc = __builtin_amdgcn_mfma_f32_16x16x32_bf16(avp, bv2, acc, 0, 0, 0);
    }
    const int orow = (lane >> 4) * 4;
    const int oc = o0 + fr;
    const float cb = conv_b[oc];
    #pragma unroll
    for (int j = 0; j < 4; ++j) {
        int r = r0 + orow + j;
        float v = acc[j] + xq_g[(size_t)r * IDIM + oc] + cb;
        xc[(size_t)r * IDIM + oc] = v;
        xcb[(size_t)r * IDIM + oc] = f2b(v);
    }
}

// ---------------------------------------------------------------------------
// k3: E = xc @ Wsg^T + bsg  (512x1536, K=512). Wave per 16x16 tile.
// ---------------------------------------------------------------------------
__global__ __launch_bounds__(256) void k3_mfma(const unsigned short* __restrict__ xcb,
                                               const unsigned short* __restrict__ Wsgb,
                                               const float* __restrict__ bsg,
                                               float* __restrict__ E) {
    const int t = threadIdx.x;
    const int w = blockIdx.x * 4 + (t >> 6);   // 0..3071
    const int lane = t & 63;
    const int mt = w / 96, nt = w % 96;
    const int r0 = mt * 16, j0 = nt * 16;
    const int fr = lane & 15, fk = (lane >> 4) * 8;
    const unsigned short* ap = xcb + (size_t)(r0 + fr) * IDIM + fk;
    const unsigned short* bp = Wsgb + (size_t)(j0 + fr) * IDIM + fk;
    f32x4 acc = {0.f, 0.f, 0.f, 0.f};
    #pragma unroll
    for (int k0 = 0; k0 < IDIM; k0 += 32) {
        bf16x8 av = *(const bf16x8*)(ap + k0);
        bf16x8 bv = *(const bf16x8*)(bp + k0);
        acc = __builtin_amdgcn_mfma_f32_16x16x32_bf16(av, bv, acc, 0, 0, 0);
    }
    const int orow = (lane >> 4) * 4;
    const int jc = j0 + fr;
    const float bias = bsg[jc];
    #pragma unroll
    for (int j = 0; j < 4; ++j)
        E[(size_t)(r0 + orow + j) * ESZ + jc] = acc[j] + bias;
}

// ---------------------------------------------------------------------------
// K3b: Cw[r,s] = sigmoid(E[r,1024+s]) * E[r,s];  u[r,i] = xc[r,i]*E[r,512+i]^2
// ---------------------------------------------------------------------------
__global__ __launch_bounds__(256) void k3b_elem(const float* __restrict__ E,
                                                const float* __restrict__ xc,
                                                float* __restrict__ Cw,
                                                float* __restrict__ u) {
    int idx4 = (blockIdx.x * 256 + threadIdx.x) * 4;  // < 512*512
    int r = idx4 >> 9, s = idx4 & 511;
    const float* Er = E + (size_t)r * ESZ;
    float4 craw = *(const float4*)&Er[s];
    float4 dw   = *(const float4*)&Er[512 + s];
    float4 graw = *(const float4*)&Er[1024 + s];
    float4 xcv  = *(const float4*)&xc[idx4];
    float4 cw, uv;
    cw.x = craw.x / (1.0f + expf(-graw.x));
    cw.y = craw.y / (1.0f + expf(-graw.y));
    cw.z = craw.z / (1.0f + expf(-graw.z));
    cw.w = craw.w / (1.0f + expf(-graw.w));
    uv.x = xcv.x * dw.x * dw.x;
    uv.y = xcv.y * dw.y * dw.y;
    uv.z = xcv.z * dw.z * dw.z;
    uv.w = xcv.w * dw.w * dw.w;
    *(float4*)&Cw[idx4] = cw;
    *(float4*)&u[idx4]  = uv;
}

// ---------------------------------------------------------------------------
// K4a: chunk-local scan, G=4 i-values per wave (u row loaded once, reused 4x).
// Wave = (b, c, ig); lane covers 8 s. 2048 waves.
// ---------------------------------------------------------------------------
__global__ __launch_bounds__(256) void k4a_pass1(const float* __restrict__ u,
                                                 const float* __restrict__ A,
                                                 float* __restrict__ C_loc) {
    const int wave = (blockIdx.x * 256 + threadIdx.x) >> 6;  // 0..2047
    const int lane = threadIdx.x & 63;
    const int ig = wave & 127;
    const int c  = (wave >> 7) & (NC - 1);
    const int b  = wave >> 10;
    const int i4 = ig * 4;
    const int s8 = lane * 8;
    float a[8][4], h[8][4];
    #pragma unroll
    for (int j = 0; j < 8; ++j) {
        float4 av = *(const float4*)&A[(size_t)(s8 + j) * IDIM + i4];
        a[j][0] = av.x; a[j][1] = av.y; a[j][2] = av.z; a[j][3] = av.w;
        h[j][0] = 0.f; h[j][1] = 0.f; h[j][2] = 0.f; h[j][3] = 0.f;
    }
    const float* ub = u + ((size_t)b * LSEQ + c * TCH) * IDIM;
    for (int l = 0; l < TCH; ++l) {
        float4 u0 = *(const float4*)(ub + l * IDIM + s8);
        float4 u1 = *(const float4*)(ub + l * IDIM + s8 + 4);
        float uu[8] = {u0.x, u0.y, u0.z, u0.w, u1.x, u1.y, u1.z, u1.w};
        #pragma unroll
        for (int ii = 0; ii < 4; ++ii)
            #pragma unroll
            for (int j = 0; j < 8; ++j)
                h[j][ii] = h[j][ii] * a[j][ii] + uu[j];
    }
    #pragma unroll
    for (int ii = 0; ii < 4; ++ii) {
        float* cp = C_loc + (((size_t)b * NC + c) * IDIM + i4 + ii) * IDIM + s8;
        float4 v0, v1;
        v0.x = h[0][ii]; v0.y = h[1][ii]; v0.z = h[2][ii]; v0.w = h[3][ii];
        v1.x = h[4][ii]; v1.y = h[5][ii]; v1.z = h[6][ii]; v1.w = h[7][ii];
        *(float4*)cp = v0;
        *(float4*)(cp + 4) = v1;
    }
}

// ---------------------------------------------------------------------------
// K4b: sequential combine IN-PLACE: C_loc[b][c] is replaced by the state
// ENTERING chunk c. h_{c} = h_{c-1} * A^TCH + carry_{c-1}, h_0 = 0.
// ---------------------------------------------------------------------------
__global__ __launch_bounds__(256) void k4b_combine(const float* __restrict__ A,
                                                   float* __restrict__ C_loc) {
    int idx = blockIdx.x * 256 + threadIdx.x;   // < 2*512*128
    int s4 = (idx & 127) * 4;
    int i  = (idx >> 7) & 511;
    int b  = idx >> 16;
    float da[4], h4[4] = {0.0f, 0.0f, 0.0f, 0.0f};
    #pragma unroll
    for (int j = 0; j < 4; ++j) {
        float aa = A[(size_t)(s4 + j) * IDIM + i];
        aa = aa * aa; aa = aa * aa; aa = aa * aa;
        aa = aa * aa; aa = aa * aa;                 // ^32 == TCH
        da[j] = aa;
    }
    for (int c = 0; c < NC; ++c) {
        size_t base = (((size_t)b * NC + c) * IDIM + i) * IDIM + s4;
        float4 cl = *(const float4*)&C_loc[base];   // carry of chunk c
        float4 hv;
        hv.x = h4[0]; hv.y = h4[1]; hv.z = h4[2]; hv.w = h4[3];
        *(float4*)&C_loc[base] = hv;                // state entering chunk c
        h4[0] = h4[0] * da[0] + cl.x;
        h4[1] = h4[1] * da[1] + cl.y;
        h4[2] = h4[2] * da[2] + cl.z;
        h4[3] = h4[3] * da[3] + cl.w;
    }
}

// ---------------------------------------------------------------------------
// K4c: seeded chunk scan + contraction, G=4 i per wave; 4 l-steps per
// butterfly batch (16 independent shfl chains). 2048 waves.
// ---------------------------------------------------------------------------
__global__ __launch_bounds__(256) void k4c_pass2(const float* __restrict__ u,
                                                 const float* __restrict__ Cw,
                                                 const float* __restrict__ A,
                                                 const float* __restrict__ D,
                                                 const float* __restrict__ H,
                                                 unsigned short* __restrict__ ybb) {
    const int wave = (blockIdx.x * 256 + threadIdx.x) >> 6;  // 0..2047
    const int lane = threadIdx.x & 63;
    const int ig = wave & 127;
    const int c  = (wave >> 7) & (NC - 1);
    const int b  = wave >> 10;
    const int i4 = ig * 4;
    const int s8 = lane * 8;
    float a[8][4], h[8][4];
    #pragma unroll
    for (int j = 0; j < 8; ++j) {
        float4 av = *(const float4*)&A[(size_t)(s8 + j) * IDIM + i4];
        a[j][0] = av.x; a[j][1] = av.y; a[j][2] = av.z; a[j][3] = av.w;
    }
    #pragma unroll
    for (int ii = 0; ii < 4; ++ii) {
        const float* hp = H + (((size_t)b * NC + c) * IDIM + i4 + ii) * IDIM + s8;
        float4 h0v = *(const float4*)hp;
        float4 h1v = *(const float4*)(hp + 4);
        h[0][ii] = h0v.x; h[1][ii] = h0v.y; h[2][ii] = h0v.z; h[3][ii] = h0v.w;
        h[4][ii] = h1v.x; h[5][ii] = h1v.y; h[6][ii] = h1v.z; h[7][ii] = h1v.w;
    }
    float4 Dv = *(const float4*)&D[i4];
    const float Di[4] = {Dv.x, Dv.y, Dv.z, Dv.w};
    const float* ub = u + (size_t)b * LSEQ * IDIM;
    const float* cb = Cw + (size_t)b * LSEQ * IDIM;
    unsigned short* yb = ybb + (size_t)b * LSEQ * IDIM;
    for (int l0 = c * TCH; l0 < c * TCH + TCH; l0 += 4) {
        float p[4][4];
        #pragma unroll
        for (int j = 0; j < 4; ++j) {
            const int l = l0 + j;
            float4 u0 = *(const float4*)(ub + l * IDIM + s8);
            float4 u1 = *(const float4*)(ub + l * IDIM + s8 + 4);
            float4 c0 = *(const float4*)(cb + l * IDIM + s8);
            float4 c1 = *(const float4*)(cb + l * IDIM + s8 + 4);
            float uu[8] = {u0.x, u0.y, u0.z, u0.w, u1.x, u1.y, u1.z, u1.w};
            float cc[8] = {c0.x, c0.y, c0.z, c0.w, c1.x, c1.y, c1.z, c1.w};
            #pragma unroll
            for (int ii = 0; ii < 4; ++ii) {
                float acc = 0.f;
                #pragma unroll
                for (int k = 0; k < 8; ++k) {
                    h[k][ii] = h[k][ii] * a[k][ii] + uu[k];
                    acc += cc[k] * h[k][ii];
                }
                p[j][ii] = acc;
            }
        }
        #pragma unroll
        for (int off = 1; off < 64; off <<= 1) {
            #pragma unroll
            for (int j = 0; j < 4; ++j)
                #pragma unroll
                for (int ii = 0; ii < 4; ++ii)
                    p[j][ii] += __shfl_xor(p[j][ii], off, 64);
        }
        if (lane == 0) {
            #pragma unroll
            for (int j = 0; j < 4; ++j) {
                float4 uli = *(const float4*)&ub[(size_t)(l0 + j) * IDIM + i4];
                const float ul[4] = {uli.x, uli.y, uli.z, uli.w};
                #pragma unroll
                for (int ii = 0; ii < 4; ++ii)
                    yb[(size_t)(l0 + j) * IDIM + i4 + ii] = f2b(p[j][ii] + ul[ii] * Di[ii]);
            }
        }
    }
}

// ---------------------------------------------------------------------------
// k5a: outlin = y @ W_out^T (512x256, K=512). Wave per 16x16 tile.
// ---------------------------------------------------------------------------
__global__ __launch_bounds__(256) void k5a_mfma(const unsigned short* __restrict__ ybb,
                                                const unsigned short* __restrict__ W_outb,
                                                float* __restrict__ outlin) {
    const int t = threadIdx.x;
    const int w = blockIdx.x * 4 + (t >> 6);   // 0..511
    const int lane = t & 63;
    const int mt = w >> 4, nt = w & 15;
    const int r0 = mt * 16, h0 = nt * 16;
    const int fr = lane & 15, fk = (lane >> 4) * 8;
    const unsigned short* ap = ybb + (size_t)(r0 + fr) * IDIM + fk;
    const unsigned short* bp = W_outb + (size_t)(h0 + fr) * IDIM + fk;
    f32x4 acc = {0.f, 0.f, 0.f, 0.f};
    #pragma unroll
    for (int k0 = 0; k0 < IDIM; k0 += 32) {
        bf16x8 av = *(const bf16x8*)(ap + k0);
        bf16x8 bv = *(const bf16x8*)(bp + k0);
        acc = __builtin_amdgcn_mfma_f32_16x16x32_bf16(av, bv, acc, 0, 0, 0);
    }
    const int orow = (lane >> 4) * 4;
    const int hc = h0 + fr;
    #pragma unroll
    for (int j = 0; j < 4; ++j)
        outlin[(size_t)(r0 + orow + j) * HDIM + hc] = acc[j];
}

// ---------------------------------------------------------------------------
// K5b: LayerNorm over H=256 + z scale + residual. One block per row.
// ---------------------------------------------------------------------------
__global__ __launch_bounds__(256) void k5b_ln(const float* __restrict__ outlin,
                                              const float* __restrict__ x,
                                              const float* __restrict__ z,
                                              const float* __restrict__ ln_g,
                                              const float* __restrict__ ln_b,
                                              float* __restrict__ out) {
    const int r = blockIdx.x;
    const int t = threadIdx.x;
    float v = outlin[(size_t)r * HDIM + t];
    float s1 = v, s2 = v * v;
    #pragma unroll
    for (int off = 1; off < 64; off <<= 1) {
        s1 += __shfl_xor(s1, off, 64);
        s2 += __shfl_xor(s2, off, 64);
    }
    __shared__ float r1[4], r2[4];
    const int w = t >> 6, lane = t & 63;
    if (lane == 0) { r1[w] = s1; r2[w] = s2; }
    __syncthreads();
    float t1 = r1[0] + r1[1] + r1[2] + r1[3];
    float t2 = r2[0] + r2[1] + r2[2] + r2[3];
    float mu = t1 * (1.0f / 256.0f);
    float var = t2 * (1.0f / 256.0f) - mu * mu;
    float inv = rsqrtf(var + 1e-5f);
    float o = (v - mu) * inv * ln_g[t] + ln_b[t];
    out[(size_t)r * HDIM + t] = o * z[0] + x[(size_t)r * HDIM + t];
}

// ---------------------------------------------------------------------------
extern "C" void kernel_launch(void* const* d_in, const int* in_sizes, int n_in,
                              void* d_out, int out_size, void* d_ws, size_t ws_size,
                              hipStream_t stream) {
    const float* x      = (const float*)d_in[0];
    const float* W_in   = (const float*)d_in[1];
    const float* conv_w = (const float*)d_in[2];
    const float* conv_b = (const float*)d_in[3];
    const float* W_ssm  = (const float*)d_in[4];
    const float* b_ssm  = (const float*)d_in[5];
    const float* W_gate = (const float*)d_in[6];
    const float* b_gate = (const float*)d_in[7];
    const float* A      = (const float*)d_in[8];
    const float* D      = (const float*)d_in[9];
    const float* W_out  = (const float*)d_in[10];
    const float* z      = (const float*)d_in[11];
    const float* ln_g   = (const float*)d_in[12];
    const float* ln_b   = (const float*)d_in[13];
    float* out = (float*)d_out;

    float* ws = (float*)d_ws;
    float*          xq_g   = ws;                               // 262144 f32
    float*          xc     = ws + 262144;                      // 262144 f32
    float*          E      = ws + 524288;                      // 786432 f32
    float*          Cw     = ws + 1310720;                     // 262144 f32
    float*          u      = ws + 1572864;                     // 262144 f32
    float*          outlin = ws + 1835008;                     // 131072 f32
    float*          bsg    = ws + 1966080;                     // 2048 f32 (1536 used)
    unsigned short* xcb    = (unsigned short*)(ws + 1968128);  // 262144 bf16
    unsigned short* xkb    = (unsigned short*)(ws + 2099200);  // 262144 bf16
    unsigned short* Wsgb   = (unsigned short*)(ws + 2230272);  // 786432 bf16
    unsigned short* W_outb = (unsigned short*)(ws + 2623488);  // 131072 bf16
    unsigned short* ybb    = (unsigned short*)(ws + 2689024);  // 262144 bf16
    // AREA: {xb, Wb, cwb} dead after kxc; reused for C_loc (NC=8, in-place H)
    float*          area   = ws + 2820096;                     // 4194304 f32
    unsigned short* xb     = (unsigned short*)area;            // 131072 bf16
    unsigned short* Wb     = (unsigned short*)(area + 65536);  // 262144 bf16
    unsigned short* cwb    = (unsigned short*)(area + 196608); // 786432 bf16
    float*          C_loc  = area;                             // 2*8*512*512 = 4194304 f32

    kcvt      <<<512, 256, 0, stream>>>(x, W_in, conv_w, W_ssm, W_gate, b_ssm,
                                        b_gate, W_out, xb, Wb, cwb, Wsgb, bsg, W_outb);
    k1_mfma   <<<512, 256, 0, stream>>>(xb, Wb, xq_g, xkb);
    kxc_mfma  <<<256, 256, 0, stream>>>(xkb, cwb, xq_g, conv_b, xc, xcb);
    k3_mfma   <<<768, 256, 0, stream>>>(xcb, Wsgb, bsg, E);
    k3b_elem  <<<256, 256, 0, stream>>>(E, xc, Cw, u);
    k4a_pass1 <<<512, 256, 0, stream>>>(u, A, C_loc);
    k4b_combine<<<512, 256, 0, stream>>>(A, C_loc);
    k4c_pass2 <<<512, 256, 0, stream>>>(u, Cw, A, D, C_loc, ybb);
    k5a_mfma  <<<128, 256, 0, stream>>>(ybb, W_outb, outlin);
    k5b_ln    <<<512, 256, 0, stream>>>(outlin, x, z, ln_g, ln_b, out);
}

// Round 8
// 103.184 us; speedup vs baseline: 1.4364x; 1.0094x over previous
//
#include <hip/hip_runtime.h>
#include <math.h>

// Problem dims
#define NB    2
#define LSEQ  256
#define HDIM  256
#define IDIM  512
#define NROW  512      // NB*LSEQ
#define NC    8        // scan chunks
#define TCH   32       // chunk length (NC*TCH == LSEQ)

typedef __attribute__((ext_vector_type(8))) short bf16x8;
typedef __attribute__((ext_vector_type(4))) float f32x4;

__device__ inline unsigned short f2b(float f) {
    unsigned u = __float_as_uint(f);
    return (unsigned short)((u + 0x7FFFu + ((u >> 16) & 1u)) >> 16);
}

// ---------------------------------------------------------------------------
// kcvt: convert x, W_in, conv_w (3 transposed planes), fused Wsg, bsg, W_out
// to bf16 staging buffers. Memory-bound, grid-stride.
// ---------------------------------------------------------------------------
__global__ __launch_bounds__(256) void kcvt(const float* __restrict__ x,
                                            const float* __restrict__ W_in,
                                            const float* __restrict__ conv_w,
                                            const float* __restrict__ W_ssm,
                                            const float* __restrict__ W_gate,
                                            const float* __restrict__ b_ssm,
                                            const float* __restrict__ b_gate,
                                            const float* __restrict__ W_out,
                                            unsigned short* __restrict__ xb,
                                            unsigned short* __restrict__ Wb,
                                            unsigned short* __restrict__ cwb,
                                            unsigned short* __restrict__ Wsgb,
                                            float* __restrict__ bsg,
                                            unsigned short* __restrict__ W_outb) {
    const int stride = gridDim.x * 256;
    const int t0 = blockIdx.x * 256 + threadIdx.x;
    for (int i = t0; i < 131072; i += stride) xb[i] = f2b(x[i]);
    for (int i = t0; i < 262144; i += stride) Wb[i] = f2b(W_in[i]);
    // cwb[k][o][i] = conv_w[o][i][k]; thread handles one (o,i), 3 planes
    for (int d = t0; d < 262144; d += stride) {
        const float* s = conv_w + (size_t)d * 3;
        cwb[d]          = f2b(s[0]);
        cwb[262144 + d] = f2b(s[1]);
        cwb[524288 + d] = f2b(s[2]);
    }
    // Wsgb rows: 0..1023 = W_ssm[512..1535]; 1024..1535 = W_gate[512..1023]
    for (int d = t0; d < 786432; d += stride) {
        int j = d >> 9, i = d & 511;
        float v = (j < 1024) ? W_ssm[(size_t)(512 + j) * 512 + i]
                             : W_gate[(size_t)(j - 512) * 512 + i];
        Wsgb[d] = f2b(v);
    }
    for (int j = t0; j < 1536; j += stride)
        bsg[j] = (j < 1024) ? b_ssm[512 + j] : b_gate[j - 512];
    for (int i = t0; i < 131072; i += stride) W_outb[i] = f2b(W_out[i]);
}

// ---------------------------------------------------------------------------
// k1: xp = x @ W_in^T (512x1024, K=256). Wave per 16x16 tile, no LDS.
// ---------------------------------------------------------------------------
__global__ __launch_bounds__(256) void k1_mfma(const unsigned short* __restrict__ xb,
                                               const unsigned short* __restrict__ Wb,
                                               float* __restrict__ xq_g,
                                               unsigned short* __restrict__ xkb) {
    const int t = threadIdx.x;
    const int w = blockIdx.x * 4 + (t >> 6);   // 0..2047
    const int lane = t & 63;
    const int mt = w >> 6, nt = w & 63;
    const int r0 = mt * 16, n0 = nt * 16;
    const int fr = lane & 15, fk = (lane >> 4) * 8;
    const unsigned short* ap = xb + (size_t)(r0 + fr) * HDIM + fk;
    const unsigned short* bp = Wb + (size_t)(n0 + fr) * HDIM + fk;
    f32x4 acc = {0.f, 0.f, 0.f, 0.f};
    #pragma unroll
    for (int k0 = 0; k0 < HDIM; k0 += 32) {
        bf16x8 av = *(const bf16x8*)(ap + k0);
        bf16x8 bv = *(const bf16x8*)(bp + k0);
        acc = __builtin_amdgcn_mfma_f32_16x16x32_bf16(av, bv, acc, 0, 0, 0);
    }
    const int orow = (lane >> 4) * 4;
    const int oc = n0 + fr;
    if (oc < IDIM) {
        #pragma unroll
        for (int j = 0; j < 4; ++j) {
            float v = acc[j];
            xq_g[(size_t)(r0 + orow + j) * IDIM + oc] =
                0.5f * v * (1.0f + erff(v * 0.70710678118654752f));
        }
    } else {
        #pragma unroll
        for (int j = 0; j < 4; ++j)
            xkb[(size_t)(r0 + orow + j) * IDIM + (oc - IDIM)] = f2b(acc[j]);
    }
}

// ---------------------------------------------------------------------------
// kxc: xc[r,o] = gelu_q[r,o] + conv_b[o] + sum_k xk[r+k-1,:]·cwb[k][o,:]
// ---------------------------------------------------------------------------
__global__ __launch_bounds__(256) void kxc_mfma(const unsigned short* __restrict__ xkb,
                                                const unsigned short* __restrict__ cwb,
                                                const float* __restrict__ xq_g,
                                                const float* __restrict__ conv_b,
                                                float* __restrict__ xc,
                                                unsigned short* __restrict__ xcb) {
    const int t = threadIdx.x;
    const int w = blockIdx.x * 4 + (t >> 6);   // 0..1023
    const int lane = t & 63;
    const int mt = w >> 5, nt = w & 31;
    const int r0 = mt * 16, o0 = nt * 16;
    const int fr = lane & 15, fk = (lane >> 4) * 8;
    const int g = r0 + fr;
    const int lo = r0 & ~255, hi = lo + 256;
    const bool okm = (g - 1 >= lo), okp = (g + 1 < hi);
    const unsigned short* am = xkb + (size_t)(g - 1) * IDIM + fk;
    const unsigned short* a0 = xkb + (size_t)g * IDIM + fk;
    const unsigned short* ap = xkb + (size_t)(g + 1) * IDIM + fk;
    const unsigned short* b0 = cwb + (size_t)(o0 + fr) * IDIM + fk;
    const unsigned short* b1 = b0 + 262144;
    const unsigned short* b2 = b0 + 524288;
    const bf16x8 zz = {0, 0, 0, 0, 0, 0, 0, 0};
    f32x4 acc = {0.f, 0.f, 0.f, 0.f};
    #pragma unroll
    for (int k0 = 0; k0 < IDIM; k0 += 32) {
        bf16x8 avm = okm ? *(const bf16x8*)(am + k0) : zz;
        bf16x8 av0 = *(const bf16x8*)(a0 + k0);
        bf16x8 avp = okp ? *(const bf16x8*)(ap + k0) : zz;
        bf16x8 bv0 = *(const bf16x8*)(b0 + k0);
        bf16x8 bv1 = *(const bf16x8*)(b1 + k0);
        bf16x8 bv2 = *(const bf16x8*)(b2 + k0);
        acc = __builtin_amdgcn_mfma_f32_16x16x32_bf16(avm, bv0, acc, 0, 0, 0);
        acc = __builtin_amdgcn_mfma_f32_16x16x32_bf16(av0, bv1, acc, 0, 0, 0);
        acc = __builtin_amdgcn_mfma_f32_16x16x32_bf16(avp, bv2, acc, 0, 0, 0);
    }
    const int orow = (lane >> 4) * 4;
    const int oc = o0 + fr;
    const float cb = conv_b[oc];
    #pragma unroll
    for (int j = 0; j < 4; ++j) {
        int r = r0 + orow + j;
        float v = acc[j] + xq_g[(size_t)r * IDIM + oc] + cb;
        xc[(size_t)r * IDIM + oc] = v;
        xcb[(size_t)r * IDIM + oc] = f2b(v);
    }
}

// ---------------------------------------------------------------------------
// k3f: fused ssm/gate GEMM + elementwise. Wave computes tiles (r0, s0),
// (r0, 512+s0), (r0, 1024+s0) of E sharing the A fragment, then:
//   Cw[r,s] = sigmoid(graw)*craw;  u[r,s] = xc[r,s]*dw*dw
// ---------------------------------------------------------------------------
__global__ __launch_bounds__(256) void k3f_mfma(const unsigned short* __restrict__ xcb,
                                                const unsigned short* __restrict__ Wsgb,
                                                const float* __restrict__ bsg,
                                                const float* __restrict__ xc,
                                                float* __restrict__ Cw,
                                                float* __restrict__ u) {
    const int t = threadIdx.x;
    const int w = blockIdx.x * 4 + (t >> 6);   // 0..1023
    const int lane = t & 63;
    const int mt = w >> 5, nt = w & 31;
    const int r0 = mt * 16, s0 = nt * 16;
    const int fr = lane & 15, fk = (lane >> 4) * 8;
    const unsigned short* ap = xcb + (size_t)(r0 + fr) * IDIM + fk;
    const unsigned short* b0 = Wsgb + (size_t)(s0 + fr) * IDIM + fk;
    const unsigned short* b1 = Wsgb + (size_t)(512 + s0 + fr) * IDIM + fk;
    const unsigned short* b2 = Wsgb + (size_t)(1024 + s0 + fr) * IDIM + fk;
    f32x4 ac0 = {0.f, 0.f, 0.f, 0.f};
    f32x4 ac1 = {0.f, 0.f, 0.f, 0.f};
    f32x4 ac2 = {0.f, 0.f, 0.f, 0.f};
    #pragma unroll
    for (int k0 = 0; k0 < IDIM; k0 += 32) {
        bf16x8 av  = *(const bf16x8*)(ap + k0);
        bf16x8 bv0 = *(const bf16x8*)(b0 + k0);
        bf16x8 bv1 = *(const bf16x8*)(b1 + k0);
        bf16x8 bv2 = *(const bf16x8*)(b2 + k0);
        ac0 = __builtin_amdgcn_mfma_f32_16x16x32_bf16(av, bv0, ac0, 0, 0, 0);
        ac1 = __builtin_amdgcn_mfma_f32_16x16x32_bf16(av, bv1, ac1, 0, 0, 0);
        ac2 = __builtin_amdgcn_mfma_f32_16x16x32_bf16(av, bv2, ac2, 0, 0, 0);
    }
    const int orow = (lane >> 4) * 4;
    const int sc = s0 + fr;
    const float bc = bsg[sc], bd = bsg[512 + sc], bg = bsg[1024 + sc];
    #pragma unroll
    for (int j = 0; j < 4; ++j) {
        int r = r0 + orow + j;
        float craw = ac0[j] + bc;
        float dw   = ac1[j] + bd;
        float graw = ac2[j] + bg;
        float gv = 1.0f / (1.0f + expf(-graw));
        float xcv = xc[(size_t)r * IDIM + sc];
        Cw[(size_t)r * IDIM + sc] = gv * craw;
        u[(size_t)r * IDIM + sc]  = xcv * dw * dw;
    }
}

// ---------------------------------------------------------------------------
// K4a: chunk-local scan, G=8 i-values per wave (u row loaded once, reused 8x).
// Wave = (b, c, ig); lane covers 8 s. 1024 waves.
// ---------------------------------------------------------------------------
__global__ __launch_bounds__(256) void k4a_pass1(const float* __restrict__ u,
                                                 const float* __restrict__ A,
                                                 float* __restrict__ C_loc) {
    const int wave = (blockIdx.x * 256 + threadIdx.x) >> 6;  // 0..1023
    const int lane = threadIdx.x & 63;
    const int ig = wave & 63;
    const int c  = (wave >> 6) & (NC - 1);
    const int b  = wave >> 9;
    const int i8 = ig * 8;
    const int s8 = lane * 8;
    float a[8][8], h[8][8];
    #pragma unroll
    for (int j = 0; j < 8; ++j) {
        float4 a0 = *(const float4*)&A[(size_t)(s8 + j) * IDIM + i8];
        float4 a1 = *(const float4*)&A[(size_t)(s8 + j) * IDIM + i8 + 4];
        a[j][0] = a0.x; a[j][1] = a0.y; a[j][2] = a0.z; a[j][3] = a0.w;
        a[j][4] = a1.x; a[j][5] = a1.y; a[j][6] = a1.z; a[j][7] = a1.w;
        #pragma unroll
        for (int ii = 0; ii < 8; ++ii) h[j][ii] = 0.f;
    }
    const float* ub = u + ((size_t)b * LSEQ + c * TCH) * IDIM;
    for (int l = 0; l < TCH; ++l) {
        float4 u0 = *(const float4*)(ub + l * IDIM + s8);
        float4 u1 = *(const float4*)(ub + l * IDIM + s8 + 4);
        float uu[8] = {u0.x, u0.y, u0.z, u0.w, u1.x, u1.y, u1.z, u1.w};
        #pragma unroll
        for (int ii = 0; ii < 8; ++ii)
            #pragma unroll
            for (int j = 0; j < 8; ++j)
                h[j][ii] = h[j][ii] * a[j][ii] + uu[j];
    }
    #pragma unroll
    for (int ii = 0; ii < 8; ++ii) {
        float* cp = C_loc + (((size_t)b * NC + c) * IDIM + i8 + ii) * IDIM + s8;
        float4 v0, v1;
        v0.x = h[0][ii]; v0.y = h[1][ii]; v0.z = h[2][ii]; v0.w = h[3][ii];
        v1.x = h[4][ii]; v1.y = h[5][ii]; v1.z = h[6][ii]; v1.w = h[7][ii];
        *(float4*)cp = v0;
        *(float4*)(cp + 4) = v1;
    }
}

// ---------------------------------------------------------------------------
// K4b: sequential combine IN-PLACE: C_loc[b][c] is replaced by the state
// ENTERING chunk c. h_{c} = h_{c-1} * A^TCH + carry_{c-1}, h_0 = 0.
// ---------------------------------------------------------------------------
__global__ __launch_bounds__(256) void k4b_combine(const float* __restrict__ A,
                                                   float* __restrict__ C_loc) {
    int idx = blockIdx.x * 256 + threadIdx.x;   // < 2*512*128
    int s4 = (idx & 127) * 4;
    int i  = (idx >> 7) & 511;
    int b  = idx >> 16;
    float da[4], h4[4] = {0.0f, 0.0f, 0.0f, 0.0f};
    #pragma unroll
    for (int j = 0; j < 4; ++j) {
        float aa = A[(size_t)(s4 + j) * IDIM + i];
        aa = aa * aa; aa = aa * aa; aa = aa * aa;
        aa = aa * aa; aa = aa * aa;                 // ^32 == TCH
        da[j] = aa;
    }
    for (int c = 0; c < NC; ++c) {
        size_t base = (((size_t)b * NC + c) * IDIM + i) * IDIM + s4;
        float4 cl = *(const float4*)&C_loc[base];   // carry of chunk c
        float4 hv;
        hv.x = h4[0]; hv.y = h4[1]; hv.z = h4[2]; hv.w = h4[3];
        *(float4*)&C_loc[base] = hv;                // state entering chunk c
        h4[0] = h4[0] * da[0] + cl.x;
        h4[1] = h4[1] * da[1] + cl.y;
        h4[2] = h4[2] * da[2] + cl.z;
        h4[3] = h4[3] * da[3] + cl.w;
    }
}

// ---------------------------------------------------------------------------
// K4c: seeded chunk scan + contraction, G=8 i per wave; 2 l-steps per
// butterfly batch (16 independent shfl chains). 1024 waves.
// ---------------------------------------------------------------------------
__global__ __launch_bounds__(256) void k4c_pass2(const float* __restrict__ u,
                                                 const float* __restrict__ Cw,
                                                 const float* __restrict__ A,
                                                 const float* __restrict__ D,
                                                 const float* __restrict__ H,
                                                 unsigned short* __restrict__ ybb) {
    const int wave = (blockIdx.x * 256 + threadIdx.x) >> 6;  // 0..1023
    const int lane = threadIdx.x & 63;
    const int ig = wave & 63;
    const int c  = (wave >> 6) & (NC - 1);
    const int b  = wave >> 9;
    const int i8 = ig * 8;
    const int s8 = lane * 8;
    float a[8][8], h[8][8];
    #pragma unroll
    for (int j = 0; j < 8; ++j) {
        float4 a0 = *(const float4*)&A[(size_t)(s8 + j) * IDIM + i8];
        float4 a1 = *(const float4*)&A[(size_t)(s8 + j) * IDIM + i8 + 4];
        a[j][0] = a0.x; a[j][1] = a0.y; a[j][2] = a0.z; a[j][3] = a0.w;
        a[j][4] = a1.x; a[j][5] = a1.y; a[j][6] = a1.z; a[j][7] = a1.w;
    }
    #pragma unroll
    for (int ii = 0; ii < 8; ++ii) {
        const float* hp = H + (((size_t)b * NC + c) * IDIM + i8 + ii) * IDIM + s8;
        float4 h0v = *(const float4*)hp;
        float4 h1v = *(const float4*)(hp + 4);
        h[0][ii] = h0v.x; h[1][ii] = h0v.y; h[2][ii] = h0v.z; h[3][ii] = h0v.w;
        h[4][ii] = h1v.x; h[5][ii] = h1v.y; h[6][ii] = h1v.z; h[7][ii] = h1v.w;
    }
    float4 D0 = *(const float4*)&D[i8];
    float4 D1 = *(const float4*)&D[i8 + 4];
    const float Di[8] = {D0.x, D0.y, D0.z, D0.w, D1.x, D1.y, D1.z, D1.w};
    const float* ub = u + (size_t)b * LSEQ * IDIM;
    const float* cb = Cw + (size_t)b * LSEQ * IDIM;
    unsigned short* yb = ybb + (size_t)b * LSEQ * IDIM;
    for (int l0 = c * TCH; l0 < c * TCH + TCH; l0 += 2) {
        float p[2][8];
        #pragma unroll
        for (int j = 0; j < 2; ++j) {
            const int l = l0 + j;
            float4 u0 = *(const float4*)(ub + l * IDIM + s8);
            float4 u1 = *(const float4*)(ub + l * IDIM + s8 + 4);
            float4 c0 = *(const float4*)(cb + l * IDIM + s8);
            float4 c1 = *(const float4*)(cb + l * IDIM + s8 + 4);
            float uu[8] = {u0.x, u0.y, u0.z, u0.w, u1.x, u1.y, u1.z, u1.w};
            float cc[8] = {c0.x, c0.y, c0.z, c0.w, c1.x, c1.y, c1.z, c1.w};
            #pragma unroll
            for (int ii = 0; ii < 8; ++ii) {
                float acc = 0.f;
                #pragma unroll
                for (int k = 0; k < 8; ++k) {
                    h[k][ii] = h[k][ii] * a[k][ii] + uu[k];
                    acc += cc[k] * h[k][ii];
                }
                p[j][ii] = acc;
            }
        }
        #pragma unroll
        for (int off = 1; off < 64; off <<= 1) {
            #pragma unroll
            for (int j = 0; j < 2; ++j)
                #pragma unroll
                for (int ii = 0; ii < 8; ++ii)
                    p[j][ii] += __shfl_xor(p[j][ii], off, 64);
        }
        if (lane == 0) {
            #pragma unroll
            for (int j = 0; j < 2; ++j) {
                float4 ul0 = *(const float4*)&ub[(size_t)(l0 + j) * IDIM + i8];
                float4 ul1 = *(const float4*)&ub[(size_t)(l0 + j) * IDIM + i8 + 4];
                const float ul[8] = {ul0.x, ul0.y, ul0.z, ul0.w,
                                     ul1.x, ul1.y, ul1.z, ul1.w};
                #pragma unroll
                for (int ii = 0; ii < 8; ++ii)
                    yb[(size_t)(l0 + j) * IDIM + i8 + ii] = f2b(p[j][ii] + ul[ii] * Di[ii]);
            }
        }
    }
}

// ---------------------------------------------------------------------------
// k5a: outlin = y @ W_out^T (512x256, K=512). Wave per 16x16 tile.
// ---------------------------------------------------------------------------
__global__ __launch_bounds__(256) void k5a_mfma(const unsigned short* __restrict__ ybb,
                                                const unsigned short* __restrict__ W_outb,
                                                float* __restrict__ outlin) {
    const int t = threadIdx.x;
    const int w = blockIdx.x * 4 + (t >> 6);   // 0..511
    const int lane = t & 63;
    const int mt = w >> 4, nt = w & 15;
    const int r0 = mt * 16, h0 = nt * 16;
    const int fr = lane & 15, fk = (lane >> 4) * 8;
    const unsigned short* ap = ybb + (size_t)(r0 + fr) * IDIM + fk;
    const unsigned short* bp = W_outb + (size_t)(h0 + fr) * IDIM + fk;
    f32x4 acc = {0.f, 0.f, 0.f, 0.f};
    #pragma unroll
    for (int k0 = 0; k0 < IDIM; k0 += 32) {
        bf16x8 av = *(const bf16x8*)(ap + k0);
        bf16x8 bv = *(const bf16x8*)(bp + k0);
        acc = __builtin_amdgcn_mfma_f32_16x16x32_bf16(av, bv, acc, 0, 0, 0);
    }
    const int orow = (lane >> 4) * 4;
    const int hc = h0 + fr;
    #pragma unroll
    for (int j = 0; j < 4; ++j)
        outlin[(size_t)(r0 + orow + j) * HDIM + hc] = acc[j];
}

// ---------------------------------------------------------------------------
// K5b: LayerNorm over H=256 + z scale + residual. One block per row.
// ---------------------------------------------------------------------------
__global__ __launch_bounds__(256) void k5b_ln(const float* __restrict__ outlin,
                                              const float* __restrict__ x,
                                              const float* __restrict__ z,
                                              const float* __restrict__ ln_g,
                                              const float* __restrict__ ln_b,
                                              float* __restrict__ out) {
    const int r = blockIdx.x;
    const int t = threadIdx.x;
    float v = outlin[(size_t)r * HDIM + t];
    float s1 = v, s2 = v * v;
    #pragma unroll
    for (int off = 1; off < 64; off <<= 1) {
        s1 += __shfl_xor(s1, off, 64);
        s2 += __shfl_xor(s2, off, 64);
    }
    __shared__ float r1[4], r2[4];
    const int w = t >> 6, lane = t & 63;
    if (lane == 0) { r1[w] = s1; r2[w] = s2; }
    __syncthreads();
    float t1 = r1[0] + r1[1] + r1[2] + r1[3];
    float t2 = r2[0] + r2[1] + r2[2] + r2[3];
    float mu = t1 * (1.0f / 256.0f);
    float var = t2 * (1.0f / 256.0f) - mu * mu;
    float inv = rsqrtf(var + 1e-5f);
    float o = (v - mu) * inv * ln_g[t] + ln_b[t];
    out[(size_t)r * HDIM + t] = o * z[0] + x[(size_t)r * HDIM + t];
}

// ---------------------------------------------------------------------------
extern "C" void kernel_launch(void* const* d_in, const int* in_sizes, int n_in,
                              void* d_out, int out_size, void* d_ws, size_t ws_size,
                              hipStream_t stream) {
    const float* x      = (const float*)d_in[0];
    const float* W_in   = (const float*)d_in[1];
    const float* conv_w = (const float*)d_in[2];
    const float* conv_b = (const float*)d_in[3];
    const float* W_ssm  = (const float*)d_in[4];
    const float* b_ssm  = (const float*)d_in[5];
    const float* W_gate = (const float*)d_in[6];
    const float* b_gate = (const float*)d_in[7];
    const float* A      = (const float*)d_in[8];
    const float* D      = (const float*)d_in[9];
    const float* W_out  = (const float*)d_in[10];
    const float* z      = (const float*)d_in[11];
    const float* ln_g   = (const float*)d_in[12];
    const float* ln_b   = (const float*)d_in[13];
    float* out = (float*)d_out;

    float* ws = (float*)d_ws;
    float*          xq_g   = ws;                               // 262144 f32
    float*          xc     = ws + 262144;                      // 262144 f32
    float*          Cw     = ws + 524288;                      // 262144 f32
    float*          u      = ws + 786432;                      // 262144 f32
    float*          outlin = ws + 1048576;                     // 131072 f32
    float*          bsg    = ws + 1179648;                     // 2048 f32 (1536 used)
    unsigned short* xcb    = (unsigned short*)(ws + 1181696);  // 262144 bf16
    unsigned short* xkb    = (unsigned short*)(ws + 1312768);  // 262144 bf16
    unsigned short* Wsgb   = (unsigned short*)(ws + 1443840);  // 786432 bf16
    unsigned short* W_outb = (unsigned short*)(ws + 1837056);  // 131072 bf16
    unsigned short* ybb    = (unsigned short*)(ws + 1902592);  // 262144 bf16
    // AREA: {xb, Wb, cwb} dead after kxc; reused for C_loc (NC=8, in-place H)
    float*          area   = ws + 2033664;                     // 4194304 f32
    unsigned short* xb     = (unsigned short*)area;            // 131072 bf16
    unsigned short* Wb     = (unsigned short*)(area + 65536);  // 262144 bf16
    unsigned short* cwb    = (unsigned short*)(area + 196608); // 786432 bf16
    float*          C_loc  = area;                             // 2*8*512*512 = 4194304 f32

    kcvt       <<<512, 256, 0, stream>>>(x, W_in, conv_w, W_ssm, W_gate, b_ssm,
                                         b_gate, W_out, xb, Wb, cwb, Wsgb, bsg, W_outb);
    k1_mfma    <<<512, 256, 0, stream>>>(xb, Wb, xq_g, xkb);
    kxc_mfma   <<<256, 256, 0, stream>>>(xkb, cwb, xq_g, conv_b, xc, xcb);
    k3f_mfma   <<<256, 256, 0, stream>>>(xcb, Wsgb, bsg, xc, Cw, u);
    k4a_pass1  <<<256, 256, 0, stream>>>(u, A, C_loc);
    k4b_combine<<<512, 256, 0, stream>>>(A, C_loc);
    k4c_pass2  <<<256, 256, 0, stream>>>(u, Cw, A, D, C_loc, ybb);
    k5a_mfma   <<<128, 256, 0, stream>>>(ybb, W_outb, outlin);
    k5b_ln     <<<512, 256, 0, stream>>>(outlin, x, z, ln_g, ln_b, out);
}